// Round 6
// baseline (28486.438 us; speedup 1.0000x reference)
//
#include <hip/hip_runtime.h>

#define TT 1000
#define HH 512
#define G4 2048
#define SPG 16        // seqs per group
#define SLOTS 32      // blocks per group
#define HCB 16        // h-cols per block (64 gate cols)

typedef __attribute__((ext_vector_type(8))) short bf16x8;
typedef __attribute__((ext_vector_type(4))) float f32x4;

__device__ __forceinline__ float sigm(float v) { return 1.0f / (1.0f + __expf(-v)); }
__device__ __forceinline__ float tanh_fast(float v) { return 2.0f / (1.0f + __expf(-2.0f * v)) - 1.0f; }

__device__ __forceinline__ unsigned short bf16rne(float f) {
    unsigned u = __float_as_uint(f);
    return (unsigned short)((u + 0x7fffu + ((u >> 16) & 1u)) >> 16);
}

// ws layout: hbuf2 u32[2][128][512] tagged-h exchange (512 KB) | ctrl u32[256] (1 KB).
// Exchange word: (bf16(h) << 16) | step_tag  -> data+readiness in one atomic u32.
// Groups self-organize by physical XCD (s_getreg XCC_ID + atomic claim); if the
// claim doesn't yield 8 groups of 32, fall back to agent-scope path (bid-derived
// groups). Producers double-store (plain -> local L2; sc1 -> IF$) so the L2-local
// fast path AND any escalation/fallback read fresh data.
__global__ __launch_bounds__(256, 1)
void lstm_l2x(const float* __restrict__ x,     // [B][T][2]
              const float* __restrict__ wih,   // [2][4H]
              const float* __restrict__ whh,   // [H][4H]
              const float* __restrict__ bias,  // [4H]
              float* __restrict__ out,         // h [B][T][H] then c [B][T][H]
              float* ws)
{
    __shared__ short hsh[16 * 512];    // h(t) bf16, swizzled (16 KB)
    __shared__ unsigned info[2];

    const int bid  = blockIdx.x;
    const int tid  = threadIdx.x;
    const int wv   = tid >> 6;
    const int lane = tid & 63;
    const int col  = lane & 15;
    const int kb   = lane >> 4;            // k-subchunk / row-group
    const int q    = col & 3;              // gate id 0=f,1=i,2=o,3=g
    const int q1   = q & 1, q2 = q >> 1;
    const int cc   = col >> 2;
    const int hl   = wv * 4 + cc;          // block h-col 0..15

    unsigned* hbuf2 = (unsigned*)ws;                          // [2][128][512]
    unsigned* ctrl  = (unsigned*)((char*)ws + 512 * 1024);    // cnt[8*16], ready@128

    // zero hsh (t=0 state)
    for (int i = tid; i < 4096; i += 256) ((unsigned*)hsh)[i] = 0u;

    // ---- one-time role claim: group by physical XCD ----
    if (tid == 0) {
        unsigned xcc;
        asm volatile("s_getreg_b32 %0, hwreg(20, 0, 32)" : "=s"(xcc));
        xcc &= 7u;
        unsigned slot = __hip_atomic_fetch_add(&ctrl[xcc * 16], 1u,
                            __ATOMIC_RELAXED, __HIP_MEMORY_SCOPE_AGENT);
        asm volatile("s_waitcnt vmcnt(0)" ::: "memory");
        __hip_atomic_fetch_add(&ctrl[128], 1u, __ATOMIC_RELAXED, __HIP_MEMORY_SCOPE_AGENT);
        long gd = 0;
        while (__hip_atomic_load(&ctrl[128], __ATOMIC_RELAXED, __HIP_MEMORY_SCOPE_AGENT) < 256u) {
            __builtin_amdgcn_s_sleep(2);
            if (++gd > 200000000L) break;
        }
        unsigned okv = 1u;
        for (int j = 0; j < 8; ++j)
            okv &= (__hip_atomic_load(&ctrl[j * 16], __ATOMIC_RELAXED,
                        __HIP_MEMORY_SCOPE_AGENT) == 32u) ? 1u : 0u;
        info[0] = (xcc << 8) | (slot & 255u);
        info[1] = okv;
    }
    __syncthreads();

    const int ok   = (int)info[1];
    const int g    = ok ? (int)(info[0] >> 8)   : (bid & 7);
    const int slot = ok ? (int)(info[0] & 255u) : (bid >> 3);

    const int gc     = q * 512 + slot * HCB + hl;   // global gate col
    const int rowSel = kb * 4 + q;                  // owned seq row (0..15)
    const int bSel   = g * SPG + rowSel;            // global batch index

    // ---- one-time: W_hh fragments into registers (64 VGPR) ----
    bf16x8 breg[16];
    #pragma unroll
    for (int kt = 0; kt < 16; ++kt) {
        bf16x8 f;
        #pragma unroll
        for (int j = 0; j < 8; ++j) {
            int k = kt * 32 + kb * 8 + j;
            f[j] = (short)bf16rne(whh[(size_t)k * G4 + gc]);
        }
        breg[kt] = f;
    }
    float wA[4], wB[4], bb[4];
    #pragma unroll
    for (int j = 0; j < 4; ++j) {
        int gcj = j * 512 + slot * HCB + hl;
        wA[j] = wih[gcj]; wB[j] = wih[G4 + gcj]; bb[j] = bias[gcj];
    }

    const int arow = col;
    const int asw  = (arow & 7) << 3;
    const short* aBase = hsh + arow * 512;

    __syncthreads();

    float cst = 0.0f;
    const size_t OSZ = (size_t)128 * TT * HH;
    const float* xp = x + (size_t)bSel * TT * 2;
    float2 xv = *(const float2*)(xp);

    for (int t = 0; t < TT; ++t) {
        // ---- gates = h @ W_hh (K=512, MFMA, 2 acc chains) ----
        f32x4 acc0 = {0.f, 0.f, 0.f, 0.f};
        f32x4 acc1 = {0.f, 0.f, 0.f, 0.f};
        #pragma unroll
        for (int kt = 0; kt < 16; kt += 2) {
            int ka = (kt * 32 + kb * 8);
            bf16x8 a0 = *(const bf16x8*)(aBase + (ka ^ asw));
            acc0 = __builtin_amdgcn_mfma_f32_16x16x32_bf16(a0, breg[kt], acc0, 0, 0, 0);
            int kc = ((kt + 1) * 32 + kb * 8);
            bf16x8 a1 = *(const bf16x8*)(aBase + (kc ^ asw));
            acc1 = __builtin_amdgcn_mfma_f32_16x16x32_bf16(a1, breg[kt + 1], acc1, 0, 0, 0);
        }
        float v0 = acc0[0] + acc1[0], v1 = acc0[1] + acc1[1];
        float v2 = acc0[2] + acc1[2], v3 = acc0[3] + acc1[3];

        // ---- quad butterfly: lane ends with all 4 gates of row rowSel ----
        float vq = q2 ? (q1 ? v3 : v2) : (q1 ? v1 : v0);
        float s1 = q2 ? (q1 ? v2 : v3) : (q1 ? v0 : v1);
        float s2 = q2 ? (q1 ? v1 : v0) : (q1 ? v3 : v2);
        float s3 = q2 ? (q1 ? v0 : v1) : (q1 ? v2 : v3);
        float g1 = __shfl_xor(s1, 1);
        float g2 = __shfl_xor(s2, 2);
        float g3 = __shfl_xor(s3, 3);

        float fv = q2 ? (q1 ? g3 : g2) : (q1 ? g1 : vq);
        float iv = q2 ? (q1 ? g2 : g3) : (q1 ? vq : g1);
        float ov = q2 ? (q1 ? g1 : vq) : (q1 ? g3 : g2);
        float gv = q2 ? (q1 ? vq : g1) : (q1 ? g2 : g3);

        fv += xv.x * wA[0] + xv.y * wB[0] + bb[0];
        iv += xv.x * wA[1] + xv.y * wB[1] + bb[1];
        ov += xv.x * wA[2] + xv.y * wB[2] + bb[2];
        gv += xv.x * wA[3] + xv.y * wB[3] + bb[3];

        float c1 = sigm(fv) * cst + sigm(iv) * tanh_fast(gv);
        float h1 = sigm(ov) * tanh_fast(c1);
        cst = c1;

        const size_t oidx = ((size_t)bSel * TT + t) * HH + slot * HCB + hl;

        if (t + 1 < TT) {
            const unsigned tag = (unsigned)(t + 1);
            // ---- producer: self-tagged word, double store ----
            {
                unsigned word = ((unsigned)bf16rne(h1) << 16) | tag;
                unsigned* dst = hbuf2 + (size_t)(((t + 1) & 1) * 128 + bSel) * 512
                              + slot * HCB + hl;
                if (ok)
                    __hip_atomic_store(dst, word, __ATOMIC_RELAXED,
                                       __HIP_MEMORY_SCOPE_WORKGROUP);   // plain -> local L2
                __hip_atomic_store(dst, word, __ATOMIC_RELAXED,
                                   __HIP_MEMORY_SCOPE_AGENT);           // sc1 -> IF$
            }
            __syncthreads();   // all hsh reads done before refill writes

            xv = *(const float2*)(xp + 2 * (t + 1));   // prefetch x(t+1)

            // ---- consumer: poll group slab (16 u64/thread) ----
            const unsigned long long tagpat =
                (unsigned long long)tag | ((unsigned long long)tag << 32);
            const unsigned long long* src = (const unsigned long long*)
                (hbuf2 + (size_t)(((t + 1) & 1) * 128 + g * SPG) * 512);
            unsigned long long vals[16];
            unsigned pend = 0xFFFFu;

            if (ok) {
                for (int sw = 0; sw < 48 && pend; ++sw) {
                    #define LD2(i) asm volatile("global_load_dwordx2 %0, %1, off sc0" \
                        : "=v"(vals[i]) : "v"(src + (i) * 256 + tid))
                    LD2(0);  LD2(1);  LD2(2);  LD2(3);
                    LD2(4);  LD2(5);  LD2(6);  LD2(7);
                    LD2(8);  LD2(9);  LD2(10); LD2(11);
                    LD2(12); LD2(13); LD2(14); LD2(15);
                    #undef LD2
                    asm volatile("s_waitcnt vmcnt(0)"
                        : "+v"(vals[0]), "+v"(vals[1]), "+v"(vals[2]), "+v"(vals[3]),
                          "+v"(vals[4]), "+v"(vals[5]), "+v"(vals[6]), "+v"(vals[7]),
                          "+v"(vals[8]), "+v"(vals[9]), "+v"(vals[10]), "+v"(vals[11]),
                          "+v"(vals[12]), "+v"(vals[13]), "+v"(vals[14]), "+v"(vals[15])
                        :: "memory");
                    pend = 0u;
                    #pragma unroll
                    for (int i = 0; i < 16; ++i)
                        if ((vals[i] ^ tagpat) & 0x0000FFFF0000FFFFULL) pend |= (1u << i);
                    if (pend) __builtin_amdgcn_s_sleep(1);
                }
            }
            // escalation / fallback: agent-scope loads for anything pending
            long gd = 0;
            while (pend) {
                #pragma unroll
                for (int i = 0; i < 16; ++i) if (pend & (1u << i)) {
                    unsigned long long v = __hip_atomic_load(src + i * 256 + tid,
                            __ATOMIC_RELAXED, __HIP_MEMORY_SCOPE_AGENT);
                    if (!((v ^ tagpat) & 0x0000FFFF0000FFFFULL)) {
                        vals[i] = v; pend &= ~(1u << i);
                    }
                }
                if (pend) { __builtin_amdgcn_s_sleep(1); if (++gd > 50000000L) break; }
            }

            // ---- refill hsh (swizzled) from tagged words ----
            #pragma unroll
            for (int i = 0; i < 16; ++i) {
                int idx = i * 256 + tid;
                int seq = idx >> 8;                 // 256 u64 per row
                int c0  = (idx & 255) * 2;
                unsigned l32 = (unsigned)((vals[i] >> 16) & 0xFFFFu)
                             | (unsigned)((vals[i] >> 32) & 0xFFFF0000u);
                *(unsigned*)(hsh + seq * 512 + (c0 ^ ((seq & 7) << 3))) = l32;
            }

            // out stores issued late: their HBM ack never blocks the chain
            out[oidx] = h1;
            out[OSZ + oidx] = c1;

            __syncthreads();
        } else {
            out[oidx] = h1;
            out[OSZ + oidx] = c1;
        }
    }
}

extern "C" void kernel_launch(void* const* d_in, const int* in_sizes, int n_in,
                              void* d_out, int out_size, void* d_ws, size_t ws_size,
                              hipStream_t stream) {
    const float* x    = (const float*)d_in[0];
    const float* wih  = (const float*)d_in[1];
    const float* whh  = (const float*)d_in[2];
    const float* bias = (const float*)d_in[3];
    float* out = (float*)d_out;
    float* ws  = (float*)d_ws;

    // zero exchange buffer (tags) + control area every launch (graph replay safe)
    hipMemsetAsync(d_ws, 0, 512 * 1024 + 1024, stream);

    dim3 grid(256), block(256);
    hipLaunchKernelGGL(lstm_l2x, grid, block, 0, stream, x, wih, whh, bias, out, ws);
}

// Round 7
// 8061.936 us; speedup vs baseline: 3.5334x; 3.5334x over previous
//
#include <hip/hip_runtime.h>

#define TT 1000
#define HH 512
#define G4 2048
#define NGRP 8
#define SPG 16        // seqs per group
#define SLOTS 32      // blocks per group
#define HCB 16        // h-cols per block (64 gate cols)

typedef __attribute__((ext_vector_type(8))) short bf16x8;
typedef __attribute__((ext_vector_type(4))) float f32x4;

__device__ __forceinline__ float sigm(float v) { return 1.0f / (1.0f + __expf(-v)); }
__device__ __forceinline__ float tanh_fast(float v) { return 2.0f / (1.0f + __expf(-2.0f * v)) - 1.0f; }

__device__ __forceinline__ unsigned short bf16rne(float f) {
    unsigned u = __float_as_uint(f);
    return (unsigned short)((u + 0x7fffu + ((u >> 16) & 1u)) >> 16);
}

// 256 blocks x 256 thr (1/CU). group g = bid&7 owns seqs [g*16,+16);
// slot = bid>>3 owns h-cols [slot*16,+16) -> 64 gate cols. W_hh in VGPRs.
// Exchange: SELF-TAGGED words, u32 = (bf16(h)<<16)|step_tag, packed 2/u64.
// No flags, no store-ack wait, no flag poll: data validates itself. Consumer
// does one batched 16-load sweep, consumes valid words into LDS immediately,
// then selectively retries only pending words. Agent scope throughout.
__global__ __launch_bounds__(256, 1)
void lstm_tag(const float* __restrict__ x,     // [B][T][2]
              const float* __restrict__ wih,   // [2][4H]
              const float* __restrict__ whh,   // [H][4H]
              const float* __restrict__ bias,  // [4H]
              float* __restrict__ out,         // h [B][T][H] then c [B][T][H]
              float* ws)
{
    __shared__ short hsh[16 * 512];    // h(t) bf16, swizzled (16 KB)

    const int bid  = blockIdx.x;
    const int g    = bid & (NGRP - 1);
    const int slot = bid >> 3;
    const int tid  = threadIdx.x;
    const int wv   = tid >> 6;
    const int lane = tid & 63;
    const int col  = lane & 15;
    const int kb   = lane >> 4;            // k-subchunk / row-group
    const int q    = col & 3;              // gate id 0=f,1=i,2=o,3=g
    const int q1   = q & 1, q2 = q >> 1;
    const int cc   = col >> 2;
    const int hl   = wv * 4 + cc;          // block h-col 0..15
    const int gc   = q * 512 + slot * HCB + hl;   // global gate col
    const int rowSel = kb * 4 + q;         // this lane's owned seq row
    const int bSel   = g * SPG + rowSel;   // global batch index

    // exchange buffer: u32[2][128][512] viewed as u64[2][128][256]
    unsigned long long* hb64 = (unsigned long long*)ws;

    // zero hsh (t=0 state)
    for (int i = tid; i < 4096; i += 256) ((unsigned*)hsh)[i] = 0u;

    // ---- one-time: W_hh fragments straight into registers (64 VGPR) ----
    bf16x8 breg[16];
    #pragma unroll
    for (int kt = 0; kt < 16; ++kt) {
        bf16x8 f;
        #pragma unroll
        for (int j = 0; j < 8; ++j) {
            int k = kt * 32 + kb * 8 + j;
            f[j] = (short)bf16rne(whh[(size_t)k * G4 + gc]);
        }
        breg[kt] = f;
    }

    float wA[4], wB[4], bb[4];
    #pragma unroll
    for (int j = 0; j < 4; ++j) {
        int gcj = j * 512 + slot * HCB + hl;
        wA[j] = wih[gcj]; wB[j] = wih[G4 + gcj]; bb[j] = bias[gcj];
    }

    const int arow = col;
    const int asw  = (arow & 7) << 3;
    const short* aBase = hsh + arow * 512;

    __syncthreads();

    float cst = 0.0f;
    const size_t OSZ = (size_t)128 * TT * HH;
    const float* xp = x + (size_t)bSel * TT * 2;
    float2 xv = *(const float2*)(xp);      // x(0) prefetched

    for (int t = 0; t < TT; ++t) {
        // ---- gates = h @ W_hh (K=512, MFMA, 2 acc chains) ----
        f32x4 acc0 = {0.f, 0.f, 0.f, 0.f};
        f32x4 acc1 = {0.f, 0.f, 0.f, 0.f};
        #pragma unroll
        for (int kt = 0; kt < 16; kt += 2) {
            int ka = (kt * 32 + kb * 8);
            bf16x8 a0 = *(const bf16x8*)(aBase + (ka ^ asw));
            acc0 = __builtin_amdgcn_mfma_f32_16x16x32_bf16(a0, breg[kt], acc0, 0, 0, 0);
            int kc = ((kt + 1) * 32 + kb * 8);
            bf16x8 a1 = *(const bf16x8*)(aBase + (kc ^ asw));
            acc1 = __builtin_amdgcn_mfma_f32_16x16x32_bf16(a1, breg[kt + 1], acc1, 0, 0, 0);
        }
        float v0 = acc0[0] + acc1[0], v1 = acc0[1] + acc1[1];
        float v2 = acc0[2] + acc1[2], v3 = acc0[3] + acc1[3];

        // ---- quad butterfly: lane ends with all 4 gates of row rowSel ----
        float vq = q2 ? (q1 ? v3 : v2) : (q1 ? v1 : v0);
        float s1 = q2 ? (q1 ? v2 : v3) : (q1 ? v0 : v1);
        float s2 = q2 ? (q1 ? v1 : v0) : (q1 ? v3 : v2);
        float s3 = q2 ? (q1 ? v0 : v1) : (q1 ? v2 : v3);
        float g1 = __shfl_xor(s1, 1);
        float g2 = __shfl_xor(s2, 2);
        float g3 = __shfl_xor(s3, 3);

        float fv = q2 ? (q1 ? g3 : g2) : (q1 ? g1 : vq);
        float iv = q2 ? (q1 ? g2 : g3) : (q1 ? vq : g1);
        float ov = q2 ? (q1 ? g1 : vq) : (q1 ? g3 : g2);
        float gv = q2 ? (q1 ? vq : g1) : (q1 ? g2 : g3);

        fv += xv.x * wA[0] + xv.y * wB[0] + bb[0];
        iv += xv.x * wA[1] + xv.y * wB[1] + bb[1];
        ov += xv.x * wA[2] + xv.y * wB[2] + bb[2];
        gv += xv.x * wA[3] + xv.y * wB[3] + bb[3];

        float c1 = sigm(fv) * cst + sigm(iv) * tanh_fast(gv);
        float h1 = sigm(ov) * tanh_fast(c1);
        cst = c1;

        // ---- register pack: cc==0 lanes gather cols hl..hl+3 of their row ----
        float hp1 = __shfl_xor(h1, 4);
        float hp2 = __shfl_xor(h1, 8);
        float hp3 = __shfl_xor(hp1, 8);
        float cp1 = __shfl_xor(c1, 4);
        float cp2 = __shfl_xor(c1, 8);
        float cp3 = __shfl_xor(cp1, 8);

        const unsigned tag = (unsigned)(t + 1);

        // ---- producer: tagged words, fire-and-forget (no ack, no flag) ----
        if (t + 1 < TT && cc == 0) {
            unsigned long long w0 =
                  (unsigned long long)(((unsigned)bf16rne(h1)  << 16) | tag)
                | ((unsigned long long)(((unsigned)bf16rne(hp1) << 16) | tag) << 32);
            unsigned long long w1 =
                  (unsigned long long)(((unsigned)bf16rne(hp2) << 16) | tag)
                | ((unsigned long long)(((unsigned)bf16rne(hp3) << 16) | tag) << 32);
            unsigned long long* dst = hb64
                + ((size_t)(((t + 1) & 1) * 128 + bSel)) * 256 + slot * 8 + wv * 2;
            __hip_atomic_store(dst,     w0, __ATOMIC_RELAXED, __HIP_MEMORY_SCOPE_AGENT);
            __hip_atomic_store(dst + 1, w1, __ATOMIC_RELAXED, __HIP_MEMORY_SCOPE_AGENT);
        }
        __syncthreads();   // all hsh reads done before refill writes

        // ---- out flush from registers (fills the visibility window) ----
        if (cc == 0) {
            size_t oidx = ((size_t)bSel * TT + t) * HH + slot * HCB + wv * 4;
            float4 hq = {h1, hp1, hp2, hp3};
            float4 cq = {c1, cp1, cp2, cp3};
            *(float4*)(out + oidx) = hq;
            *(float4*)(out + OSZ + oidx) = cq;
        }

        if (t + 1 < TT) {
            xv = *(const float2*)(xp + 2 * (t + 1));   // prefetch x(t+1)

            // ---- consumer: batched tagged sweep + selective retry ----
            const unsigned long long tagpat =
                (unsigned long long)tag | ((unsigned long long)tag << 32);
            const unsigned long long* src = hb64
                + ((size_t)(((t + 1) & 1) * 128 + g * SPG)) * 256;

            unsigned long long vals[16];
            #pragma unroll
            for (int i = 0; i < 16; ++i)
                vals[i] = __hip_atomic_load(src + i * 256 + tid,
                              __ATOMIC_RELAXED, __HIP_MEMORY_SCOPE_AGENT);

            unsigned pend = 0u;
            #pragma unroll
            for (int i = 0; i < 16; ++i) {
                int idx = i * 256 + tid;
                int seq = idx >> 8;              // 256 u64 per row
                int c0  = (idx & 255) * 2;
                if (!((vals[i] ^ tagpat) & 0x0000FFFF0000FFFFULL)) {
                    unsigned pk = (unsigned)((vals[i] >> 16) & 0xFFFFu)
                                | (unsigned)((vals[i] >> 48) << 16);
                    *(unsigned*)(hsh + seq * 512 + (c0 ^ ((seq & 7) << 3))) = pk;
                } else {
                    pend |= (1u << i);
                }
            }

            long gd = 0;
            while (pend) {
                #pragma unroll
                for (int i = 0; i < 16; ++i) if (pend & (1u << i)) {
                    unsigned long long w = __hip_atomic_load(src + i * 256 + tid,
                            __ATOMIC_RELAXED, __HIP_MEMORY_SCOPE_AGENT);
                    if (!((w ^ tagpat) & 0x0000FFFF0000FFFFULL)) {
                        int idx = i * 256 + tid;
                        int seq = idx >> 8;
                        int c0  = (idx & 255) * 2;
                        unsigned pk = (unsigned)((w >> 16) & 0xFFFFu)
                                    | (unsigned)((w >> 48) << 16);
                        *(unsigned*)(hsh + seq * 512 + (c0 ^ ((seq & 7) << 3))) = pk;
                        pend &= ~(1u << i);
                    }
                }
                if (pend) {
                    __builtin_amdgcn_s_sleep(1);
                    if (++gd > 20000000L) break;   // anti-hang escape
                }
            }

            __syncthreads();
        }
    }
}

extern "C" void kernel_launch(void* const* d_in, const int* in_sizes, int n_in,
                              void* d_out, int out_size, void* d_ws, size_t ws_size,
                              hipStream_t stream) {
    const float* x    = (const float*)d_in[0];
    const float* wih  = (const float*)d_in[1];
    const float* whh  = (const float*)d_in[2];
    const float* bias = (const float*)d_in[3];
    float* out = (float*)d_out;
    float* ws  = (float*)d_ws;

    // zero the tagged exchange buffer every launch (graph replay safe)
    hipMemsetAsync(d_ws, 0, 512 * 1024, stream);

    dim3 grid(256), block(256);
    hipLaunchKernelGGL(lstm_tag, grid, block, 0, stream, x, wih, whh, bias, out, ws);
}